// Round 1
// baseline (149.888 us; speedup 1.0000x reference)
//
#include <hip/hip_runtime.h>
#include <math.h>

#define CE_B 4096
#define CE_V 50257
#define NTHREADS 256

// Merge two (max, sumexp) online-softmax states.
__device__ inline void lse_merge(float& m, float& s, float mo, float so) {
    float M = fmaxf(m, mo);
    s = s * __expf(m - M) + so * __expf(mo - M);
    m = M;
}

__global__ __launch_bounds__(NTHREADS) void ce_row_kernel(const float* __restrict__ labels,
                                                          const int* __restrict__ truth,
                                                          float* __restrict__ partial) {
    const int b = blockIdx.x;
    const long long rowbase = (long long)b * CE_V;
    const float* __restrict__ row = labels + rowbase;
    const int tid = threadIdx.x;

    // Align to 16B: row base element index is b*50257 (odd for odd b).
    const int misalign = (int)(rowbase & 3);
    const int pro = (4 - misalign) & 3;   // scalar prologue elements

    float m = -INFINITY;
    float s = 0.0f;

    if (tid < pro) {
        m = row[tid];
        s = 1.0f;
    }

    const float4* __restrict__ vrow = reinterpret_cast<const float4*>(row + pro);
    const int nvec = (CE_V - pro) >> 2;          // float4 count (~12563) >> NTHREADS, so every thread gets work
    const int tail_start = pro + (nvec << 2);

    for (int i = tid; i < nvec; i += NTHREADS) {
        float4 v = vrow[i];
        float m4 = fmaxf(fmaxf(v.x, v.y), fmaxf(v.z, v.w));
        if (m4 > m) {                            // rare: O(log n) times per thread
            s *= __expf(m - m4);                 // m=-inf first time -> exp(-inf)=0, s=0 anyway
            m = m4;
        }
        s += __expf(v.x - m) + __expf(v.y - m) + __expf(v.z - m) + __expf(v.w - m);
    }
    for (int i = tail_start + tid; i < CE_V; i += NTHREADS) {
        float x = row[i];
        if (x > m) { s *= __expf(m - x); m = x; }
        s += __expf(x - m);
    }

    // Wave64 butterfly merge. Every thread processed >=1 vec element, so m is finite (no inf-inf NaN).
    for (int off = 32; off >= 1; off >>= 1) {
        float mo = __shfl_xor(m, off);
        float so = __shfl_xor(s, off);
        lse_merge(m, s, mo, so);
    }

    __shared__ float sm[NTHREADS / 64], ss[NTHREADS / 64];
    const int wave = tid >> 6, lane = tid & 63;
    if (lane == 0) { sm[wave] = m; ss[wave] = s; }
    __syncthreads();

    if (tid == 0) {
        float M = sm[0], S = ss[0];
        #pragma unroll
        for (int w = 1; w < NTHREADS / 64; ++w) lse_merge(M, S, sm[w], ss[w]);
        float lse = M + __logf(S);
        float picked = row[truth[b]];
        partial[b] = lse - picked;
    }
}

__global__ __launch_bounds__(NTHREADS) void ce_reduce_kernel(const float* __restrict__ partial,
                                                             float* __restrict__ out) {
    const int tid = threadIdx.x;
    float acc = 0.0f;
    for (int i = tid; i < CE_B; i += NTHREADS) acc += partial[i];
    for (int off = 32; off >= 1; off >>= 1) acc += __shfl_xor(acc, off);

    __shared__ float ws[NTHREADS / 64];
    const int wave = tid >> 6, lane = tid & 63;
    if (lane == 0) ws[wave] = acc;
    __syncthreads();
    if (tid == 0) {
        float t = 0.0f;
        #pragma unroll
        for (int w = 0; w < NTHREADS / 64; ++w) t += ws[w];
        out[0] = t / (float)CE_B;
    }
}

extern "C" void kernel_launch(void* const* d_in, const int* in_sizes, int n_in,
                              void* d_out, int out_size, void* d_ws, size_t ws_size,
                              hipStream_t stream) {
    const float* labels = (const float*)d_in[0];
    const int* truth    = (const int*)d_in[1];
    float* out          = (float*)d_out;
    float* partial      = (float*)d_ws;   // CE_B floats = 16 KB

    ce_row_kernel<<<CE_B, NTHREADS, 0, stream>>>(labels, truth, partial);
    ce_reduce_kernel<<<1, NTHREADS, 0, stream>>>(partial, out);
}

// Round 2
// 138.350 us; speedup vs baseline: 1.0834x; 1.0834x over previous
//
#include <hip/hip_runtime.h>
#include <math.h>

#define CE_B 4096
#define CE_V 50257
#define NTHREADS 256

typedef float f32x4 __attribute__((ext_vector_type(4)));

// Merge two (max, sumexp) online-softmax states.
__device__ inline void lse_merge(float& m, float& s, float mo, float so) {
    float M = fmaxf(m, mo);
    s = s * __expf(m - M) + so * __expf(mo - M);
    m = M;
}

__global__ __launch_bounds__(NTHREADS) void ce_row_kernel(const float* __restrict__ labels,
                                                          const int* __restrict__ truth,
                                                          float* __restrict__ partial) {
    const int b = blockIdx.x;
    const long long rowbase = (long long)b * CE_V;
    const float* __restrict__ row = labels + rowbase;
    const int tid = threadIdx.x;

    // Align to 16B: row base element index is b*50257 (odd for odd b).
    const int misalign = (int)(rowbase & 3);
    const int pro = (4 - misalign) & 3;   // scalar prologue elements

    float m = -INFINITY;
    float s = 0.0f;

    if (tid < pro) {
        m = row[tid];
        s = 1.0f;
    }

    const f32x4* __restrict__ vrow = reinterpret_cast<const f32x4*>(row + pro);
    const int nvec = (CE_V - pro) >> 2;          // ~12563 float4s; every thread gets >=49
    const int tail_start = pro + (nvec << 2);

    // Main loop: 2 nontemporal float4 loads per iteration (8 elems), one
    // combined max-branch. nt bypasses cache fill — data is read-once, >L3.
    int i = tid;
    for (; i + NTHREADS < nvec; i += 2 * NTHREADS) {
        f32x4 v0 = __builtin_nontemporal_load(vrow + i);
        f32x4 v1 = __builtin_nontemporal_load(vrow + i + NTHREADS);
        float m8 = fmaxf(fmaxf(fmaxf(v0.x, v0.y), fmaxf(v0.z, v0.w)),
                         fmaxf(fmaxf(v1.x, v1.y), fmaxf(v1.z, v1.w)));
        if (m8 > m) {                            // rare: O(log n) per thread
            s *= __expf(m - m8);                 // m=-inf first time -> 0, s=0 anyway
            m = m8;
        }
        s += ((__expf(v0.x - m) + __expf(v0.y - m)) + (__expf(v0.z - m) + __expf(v0.w - m)))
           + ((__expf(v1.x - m) + __expf(v1.y - m)) + (__expf(v1.z - m) + __expf(v1.w - m)));
    }
    if (i < nvec) {
        f32x4 v0 = __builtin_nontemporal_load(vrow + i);
        float m4 = fmaxf(fmaxf(v0.x, v0.y), fmaxf(v0.z, v0.w));
        if (m4 > m) { s *= __expf(m - m4); m = m4; }
        s += (__expf(v0.x - m) + __expf(v0.y - m)) + (__expf(v0.z - m) + __expf(v0.w - m));
    }
    for (int j = tail_start + tid; j < CE_V; j += NTHREADS) {
        float x = row[j];
        if (x > m) { s *= __expf(m - x); m = x; }
        s += __expf(x - m);
    }

    // Wave64 butterfly merge. Every thread processed >=1 vec element -> m finite.
    for (int off = 32; off >= 1; off >>= 1) {
        float mo = __shfl_xor(m, off);
        float so = __shfl_xor(s, off);
        lse_merge(m, s, mo, so);
    }

    __shared__ float sm[NTHREADS / 64], ss[NTHREADS / 64];
    const int wave = tid >> 6, lane = tid & 63;
    if (lane == 0) { sm[wave] = m; ss[wave] = s; }
    __syncthreads();

    if (tid == 0) {
        float M = sm[0], S = ss[0];
        #pragma unroll
        for (int w = 1; w < NTHREADS / 64; ++w) lse_merge(M, S, sm[w], ss[w]);
        float lse = M + __logf(S);
        float picked = row[truth[b]];
        partial[b] = lse - picked;
    }
}

__global__ __launch_bounds__(NTHREADS) void ce_reduce_kernel(const float* __restrict__ partial,
                                                             float* __restrict__ out) {
    const int tid = threadIdx.x;
    float acc = 0.0f;
    for (int i = tid; i < CE_B; i += NTHREADS) acc += partial[i];
    for (int off = 32; off >= 1; off >>= 1) acc += __shfl_xor(acc, off);

    __shared__ float ws[NTHREADS / 64];
    const int wave = tid >> 6, lane = tid & 63;
    if (lane == 0) ws[wave] = acc;
    __syncthreads();
    if (tid == 0) {
        float t = 0.0f;
        #pragma unroll
        for (int w = 0; w < NTHREADS / 64; ++w) t += ws[w];
        out[0] = t / (float)CE_B;
    }
}

extern "C" void kernel_launch(void* const* d_in, const int* in_sizes, int n_in,
                              void* d_out, int out_size, void* d_ws, size_t ws_size,
                              hipStream_t stream) {
    const float* labels = (const float*)d_in[0];
    const int* truth    = (const int*)d_in[1];
    float* out          = (float*)d_out;
    float* partial      = (float*)d_ws;   // CE_B floats = 16 KB

    ce_row_kernel<<<CE_B, NTHREADS, 0, stream>>>(labels, truth, partial);
    ce_reduce_kernel<<<1, NTHREADS, 0, stream>>>(partial, out);
}